// Round 1
// 157.000 us; speedup vs baseline: 1.0913x; 1.0913x over previous
//
#include <hip/hip_runtime.h>
#include <math.h>

#define B_ 64
#define I_ 4096
#define P_ 8      // Din
#define N_ 10
#define D_ 16
#define ND_ 160   // N*D
#define BND_ (B_*ND_)   // 10240
#define EPS_ 1e-7f

#define IPB_ 8                 // i per block
#define NBLK_ (I_ / IPB_)      // 512 blocks = 2 blocks/CU
#define WTILE_ (N_ * P_ * D_)  // 1280 floats of W per i (global, unpadded)
#define NSTR_ 144              // padded n-stride in LDS (floats): odd n -> bank+16
#define ILSTR_ (N_ * NSTR_)    // 1440 floats per i in LDS

// DPP cross-lane value fetch on the VALU pipe (no DS traffic).
// 0xB1 quad_perm [1,0,3,2] = xor1; 0x4E quad_perm [2,3,0,1] = xor2;
// 0x141 row_half_mirror = xor7 within 8 (valid as xor4 once bits0-1 uniform);
// 0x140 row_mirror = xor15 within 16 (valid as xor8 once bits0-2 uniform).
template<int CTRL>
__device__ __forceinline__ float dpp_bcast(float v) {
    int r = __builtin_amdgcn_update_dpp(0, __float_as_int(v), CTRL, 0xF, 0xF, true);
    return __int_as_float(r);
}

// Round-13: 4-b-per-thread W-read amortization (theory: R12's ~47 us/pass is
// LDS return bandwidth -- 80 ds_read_b128/thread-il = 5.24 MB/CU delivered,
// 16x redundant (each W element re-read per b), PLUS a 2-way bank conflict on
// b128 (np partner at +512 B = same banks)).
//  - lane = ds(3b: d-pair) | np(1b) | bl2(2b). Thread owns b = wv*16+bl2*4+j
//    (j=0..3), n = np+2k (5 n's), d = 2ds..2ds+1.
//  - W read: one ds_read_b64 per (k,p) feeds 8 FMAs (4 b x 2 d): 40 b64 =
//    320 B/thread-il (was 1280 B) -> 1.31 MB/CU delivered (~5 us).
//  - LDS n-stride padded to 144 floats (576 B): odd n at bank+16, so the 16
//    unique b64 addresses/instr hit all 32 banks once, broadcast x4 -> zero
//    conflicts.
//  - d-dot spans 8 ds lanes: DPP butterfly xor1, xor2, row_half_mirror.
//    Softmax max/expsum combine across np: row_mirror. All VALU-pipe.
//  - x direct from global (16 lanes broadcast one 32 B address), prefetched
//    one il ahead (R12 pattern). Single barrier (W stage) kept.
// __launch_bounds__(256, 2) -- R2-proven; do NOT tighten (R3: cap-64 spill).
// NO cooperative launch (R11: grid.sync deadlocked the harness).
template<int MODE>
__global__ __launch_bounds__(256, 2)
void digitcaps_pass(const float* __restrict__ x, const float* __restrict__ W,
                    const float* __restrict__ Vc, float* __restrict__ part)
{
    __shared__ float wsh[IPB_ * ILSTR_];   // 11520 floats = 46080 B
    const int t = threadIdx.x;
    const int lane = t & 63;
    const int ds  = lane & 7;              // d-pair index: d = 2ds, 2ds+1
    const int np  = (lane >> 3) & 1;       // n-parity (owns n = np+2k)
    const int bl2 = lane >> 4;             // 0..3
    const int wv  = t >> 6;                // 0..3
    const int bb  = wv * 16 + bl2 * 4;     // first of this thread's 4 b's
    const int i0  = blockIdx.x * IPB_;

    // ---- stage W[i0..i0+8) into padded LDS: 2560 float4, 10/thread ----
    // global chunk c -> il = c/320, r = c%320, n = r/32, s = r%32
    // dst float4 = il*360 + n*36 + s  (floats: il*1440 + n*144 + s*4)
    {
        const float4* __restrict__ Wg = (const float4*)(W + (size_t)i0 * WTILE_);
        float4* __restrict__ Ws = (float4*)wsh;
#pragma unroll
        for (int c0 = 0; c0 < (IPB_ * WTILE_) / (4 * 256); ++c0) {  // 10
            int c  = c0 * 256 + t;
            int il = c / 320;
            int r  = c - il * 320;
            int n  = r >> 5;
            int s  = r & 31;
            Ws[il * 360 + n * 36 + s] = Wg[c];
        }
    }

    float vc[4][5][2];
    if (MODE == 1) {
#pragma unroll
        for (int j = 0; j < 4; ++j)
#pragma unroll
            for (int k = 0; k < 5; ++k) {
                const float2* vp = (const float2*)(Vc + (size_t)(bb + j) * ND_
                                                   + (np + 2 * k) * D_ + 2 * ds);
                float2 v = *vp;
                vc[j][k][0] = v.x; vc[j][k][1] = v.y;
            }
    }

    float acc[4][5][2];
#pragma unroll
    for (int j = 0; j < 4; ++j)
#pragma unroll
        for (int k = 0; k < 5; ++k) { acc[j][k][0] = 0.f; acc[j][k][1] = 0.f; }

    // preload x for il=0: 4 b's, 16 lanes broadcast each 32 B chunk
    float xv[4][P_];
#pragma unroll
    for (int j = 0; j < 4; ++j) {
        const float4* xp = (const float4*)(x + ((size_t)(bb + j) * I_ + i0) * P_);
        float4 a0 = xp[0], a1 = xp[1];
        xv[j][0]=a0.x; xv[j][1]=a0.y; xv[j][2]=a0.z; xv[j][3]=a0.w;
        xv[j][4]=a1.x; xv[j][5]=a1.y; xv[j][6]=a1.z; xv[j][7]=a1.w;
    }

    __syncthreads();   // ONLY barrier in the kernel (W staged)

#pragma unroll 1
    for (int il = 0; il < IPB_; ++il) {
        // one vaddr + compile-time ds_read offsets (k*288 + p*16 floats)
        const float* __restrict__ Wb = wsh + il * ILSTR_ + np * NSTR_ + 2 * ds;

        // u_hat fragments tv[j][k][d]: 40 ds_read_b64, 320 FMA
        float tv[4][5][2];
#pragma unroll
        for (int k = 0; k < 5; ++k) {
#pragma unroll
            for (int j = 0; j < 4; ++j) { tv[j][k][0] = 0.f; tv[j][k][1] = 0.f; }
#pragma unroll
            for (int p = 0; p < P_; ++p) {
                float2 w = *(const float2*)(Wb + k * 2 * NSTR_ + p * D_);
#pragma unroll
                for (int j = 0; j < 4; ++j) {
                    tv[j][k][0] = fmaf(w.x, xv[j][p], tv[j][k][0]);
                    tv[j][k][1] = fmaf(w.y, xv[j][p], tv[j][k][1]);
                }
            }
        }

        // prefetch x for il+1 (no barrier anywhere to force its drain)
        float xn[4][P_];
        if (il + 1 < IPB_) {
#pragma unroll
            for (int j = 0; j < 4; ++j) {
                const float4* xp = (const float4*)(x + ((size_t)(bb + j) * I_
                                                        + i0 + il + 1) * P_);
                float4 a0 = xp[0], a1 = xp[1];
                xn[j][0]=a0.x; xn[j][1]=a0.y; xn[j][2]=a0.z; xn[j][3]=a0.w;
                xn[j][4]=a1.x; xn[j][5]=a1.y; xn[j][6]=a1.z; xn[j][7]=a1.w;
            }
        }

        if (MODE == 0) {
            // uniform c (softmax of zeros) -> 0.1 scale applied in reduce
#pragma unroll
            for (int j = 0; j < 4; ++j)
#pragma unroll
                for (int k = 0; k < 5; ++k) {
                    acc[j][k][0] += tv[j][k][0];
                    acc[j][k][1] += tv[j][k][1];
                }
        } else {
#pragma unroll
            for (int j = 0; j < 4; ++j) {
                // full d-dot via DPP butterfly over the 8 ds lanes
                float e[5];
                float m = -1e30f;
#pragma unroll
                for (int k = 0; k < 5; ++k) {
                    float l = fmaf(tv[j][k][1], vc[j][k][1],
                                   tv[j][k][0] * vc[j][k][0]);
                    l += dpp_bcast<0xB1>(l);    // + xor1 (d-pairs)
                    l += dpp_bcast<0x4E>(l);    // + xor2
                    l += dpp_bcast<0x141>(l);   // + xor4 (half-mirror) -> full dot
                    e[k] = l;
                    m = fmaxf(m, l);
                }
                m = fmaxf(m, dpp_bcast<0x140>(m));   // max over other n-parity
                float se = 0.f;
#pragma unroll
                for (int k = 0; k < 5; ++k) { e[k] = __expf(e[k] - m); se += e[k]; }
                se += dpp_bcast<0x140>(se);          // + other parity's expsum
                float inv = 1.f / se;
#pragma unroll
                for (int k = 0; k < 5; ++k) {
                    float cn = e[k] * inv;
                    acc[j][k][0] = fmaf(cn, tv[j][k][0], acc[j][k][0]);
                    acc[j][k][1] = fmaf(cn, tv[j][k][1], acc[j][k][1]);
                }
            }
        }

        if (il + 1 < IPB_) {
#pragma unroll
            for (int j = 0; j < 4; ++j)
#pragma unroll
                for (int p = 0; p < P_; ++p) xv[j][p] = xn[j][p];
        }
    }

    // store partials in NATURAL layout part[blk][b][n][d]; 20 float2/thread
    // (lanes 0-15 cover 128 contiguous B per bl2 group)
#pragma unroll
    for (int j = 0; j < 4; ++j) {
        float* __restrict__ dst = part + (size_t)blockIdx.x * BND_
                                  + (size_t)(bb + j) * ND_ + np * D_ + 2 * ds;
#pragma unroll
        for (int k = 0; k < 5; ++k) {
            float2 s2; s2.x = acc[j][k][0]; s2.y = acc[j][k][1];
            *(float2*)(dst + k * 2 * D_) = s2;
        }
    }
}

// Parallel-wide reduce over part rows (natural layout [row][b*160+nd]).
// Block handles 16 outputs; 16 tp-threads per output sum 32 rows each with
// coalesced loads; shfl+LDS tree. (unchanged from R12)
__global__ __launch_bounds__(256)
void digitcaps_reduce(const float* __restrict__ part, float scale, int mode,
                      float* __restrict__ Vc, float* __restrict__ out)
{
    __shared__ float sm[4][16];
    const int t = threadIdx.x;
    const int kk = t & 15;
    const int tp = t >> 4;                 // 0..15
    const int k = blockIdx.x * 16 + kk;    // natural [b][n][d] index

    float s = 0.f;
    const float* __restrict__ p0 = part + (size_t)tp * BND_ + k;
#pragma unroll 8
    for (int j = 0; j < NBLK_ / 16; ++j)   // 32 rows per tp-thread
        s += p0[(size_t)j * 16 * BND_];

    s += __shfl_down(s, 32);
    s += __shfl_down(s, 16);
    if ((t & 63) < 16) sm[t >> 6][kk] = s;
    __syncthreads();

    if (t < 16) {
        float tot = (sm[0][t] + sm[1][t]) + (sm[2][t] + sm[3][t]);
        tot *= scale;
        float sq = tot * tot;
        float v = tot * (sq / ((1.f + sq) * sqrtf(sq + EPS_)));
        int j = blockIdx.x * 16 + t;       // natural layout: output index = k
        if (mode == 0)      Vc[j] = v;     // after iter 0: Vc = v0
        else if (mode == 1) Vc[j] += v;    // after iter 1: Vc = v0 + v1
        else                out[j] = v;    // final output [B,N,1,D]
    }
}

extern "C" void kernel_launch(void* const* d_in, const int* in_sizes, int n_in,
                              void* d_out, int out_size, void* d_ws, size_t ws_size,
                              hipStream_t stream)
{
    const float* x = (const float*)d_in[0];   // [64, 4096, 8] f32
    const float* W = (const float*)d_in[1];   // [4096, 10, 8, 16] f32
    float* out = (float*)d_out;               // [64, 10, 1, 16] f32

    // ws: part (512*10240 f = 21 MB) | Vc (10240 f)
    float* part = (float*)d_ws;
    float* Vc   = part + (size_t)NBLK_ * BND_;

    dim3 pblk(256), pgrid(NBLK_), rblk(256), rgrid(BND_ / 16);

    for (int pass = 0; pass < 3; ++pass) {
        if (pass == 0)
            digitcaps_pass<0><<<pgrid, pblk, 0, stream>>>(x, W, nullptr, part);
        else
            digitcaps_pass<1><<<pgrid, pblk, 0, stream>>>(x, W, Vc, part);
        digitcaps_reduce<<<rgrid, rblk, 0, stream>>>(part, pass == 0 ? 0.1f : 1.0f,
                                                     pass, Vc, out);
    }
}